// Round 7
// baseline (164.261 us; speedup 1.0000x reference)
//
#include <hip/hip_runtime.h>

typedef __attribute__((ext_vector_type(8))) short short8;
typedef __attribute__((ext_vector_type(4))) float f32x4;

#define B_ 2
#define S_ 512
#define D_ 768
#define NH 12
#define HD 64

__device__ inline short f2bf(float f) {
    union { float f; unsigned u; } v; v.f = f;
    unsigned r = v.u + 0x7fffu + ((v.u >> 16) & 1u);
    return (short)(r >> 16);
}

// Async global -> LDS, 16 B per lane. Dest is wave-uniform base + lane*16.
__device__ __forceinline__ void gl16(const float* g, float* l) {
    __builtin_amdgcn_global_load_lds(
        (const __attribute__((address_space(1))) float*)(g),
        (__attribute__((address_space(3))) float*)(l), 16, 0, 0);
}

// ---------------------------------------------------------------------------
// Kernel 1: QKV projection, bf16 MFMA (16x16x32), fp32 accumulate.
// q -> qbf (bf16, pre-scaled 1/8), k -> kbf (bf16), v -> vws (fp32),
// all in (B, NH, S, HD) layout.
// ---------------------------------------------------------------------------
__global__ __launch_bounds__(256) void qkv_gemm(
    const float* __restrict__ hidden,
    const float* __restrict__ Wq, const float* __restrict__ Wk, const float* __restrict__ Wv,
    const float* __restrict__ bq, const float* __restrict__ bk, const float* __restrict__ bv,
    short* __restrict__ qbf, short* __restrict__ kbf, float* __restrict__ vws)
{
    __shared__ short hs[64 * 72];
    __shared__ short wt[64 * 72];

    const int mt = blockIdx.x, nt = blockIdx.y, mat = blockIdx.z;
    const int m0 = mt * 64, n0 = nt * 64;
    const float* W    = (mat == 0) ? Wq : ((mat == 1) ? Wk : Wv);
    const float* bias = (mat == 0) ? bq : ((mat == 1) ? bk : bv);

    const int tid = threadIdx.x;
    const int w = tid >> 6, l = tid & 63;
    const int sr = tid >> 2, sc = (tid & 3) * 16;

    f32x4 acc[4];
    #pragma unroll
    for (int i = 0; i < 4; ++i) acc[i] = (f32x4){0.f, 0.f, 0.f, 0.f};

    const int arow = (w * 16 + (l & 15)) * 72 + (l >> 4) * 8;

    for (int kt = 0; kt < 12; ++kt) {
        const int d0 = kt * 64;
        if (kt) __syncthreads();
        {
            const float4* sa = (const float4*)(hidden + (size_t)(m0 + sr) * D_ + d0 + sc);
            float4 x0 = sa[0], x1 = sa[1], x2 = sa[2], x3 = sa[3];
            short8 p0 = {f2bf(x0.x), f2bf(x0.y), f2bf(x0.z), f2bf(x0.w),
                         f2bf(x1.x), f2bf(x1.y), f2bf(x1.z), f2bf(x1.w)};
            short8 p1 = {f2bf(x2.x), f2bf(x2.y), f2bf(x2.z), f2bf(x2.w),
                         f2bf(x3.x), f2bf(x3.y), f2bf(x3.z), f2bf(x3.w)};
            *(short8*)&hs[sr * 72 + sc]     = p0;
            *(short8*)&hs[sr * 72 + sc + 8] = p1;
            const float4* sb = (const float4*)(W + (size_t)(n0 + sr) * D_ + d0 + sc);
            float4 y0 = sb[0], y1 = sb[1], y2 = sb[2], y3 = sb[3];
            short8 q0 = {f2bf(y0.x), f2bf(y0.y), f2bf(y0.z), f2bf(y0.w),
                         f2bf(y1.x), f2bf(y1.y), f2bf(y1.z), f2bf(y1.w)};
            short8 q1 = {f2bf(y2.x), f2bf(y2.y), f2bf(y2.z), f2bf(y2.w),
                         f2bf(y3.x), f2bf(y3.y), f2bf(y3.z), f2bf(y3.w)};
            *(short8*)&wt[sr * 72 + sc]     = q0;
            *(short8*)&wt[sr * 72 + sc + 8] = q1;
        }
        __syncthreads();
        short8 a0 = *(const short8*)&hs[arow];
        short8 a1 = *(const short8*)&hs[arow + 32];
        #pragma unroll
        for (int ct = 0; ct < 4; ++ct) {
            const int brow = (ct * 16 + (l & 15)) * 72 + (l >> 4) * 8;
            short8 b0 = *(const short8*)&wt[brow];
            short8 b1 = *(const short8*)&wt[brow + 32];
            acc[ct] = __builtin_amdgcn_mfma_f32_16x16x32_bf16(a0, b0, acc[ct], 0, 0, 0);
            acc[ct] = __builtin_amdgcn_mfma_f32_16x16x32_bf16(a1, b1, acc[ct], 0, 0, 0);
        }
    }

    #pragma unroll
    for (int ct = 0; ct < 4; ++ct) {
        #pragma unroll
        for (int rr = 0; rr < 4; ++rr) {
            const int m_l = w * 16 + (l >> 4) * 4 + rr;
            const int n_l = ct * 16 + (l & 15);
            const int m = m0 + m_l;
            const int b = m >> 9, s = m & 511;
            float v = acc[ct][rr] + bias[n0 + n_l];
            const size_t dst = (((size_t)(b * NH + nt) * S_) + s) * HD + n_l;
            if (mat == 0)      qbf[dst] = f2bf(v * 0.125f);
            else if (mat == 1) kbf[dst] = f2bf(v);
            else               vws[dst] = v;
        }
    }
}

// ---------------------------------------------------------------------------
// Kernel 2: scores = qs . K^T + mask, batched over (b,n). 64x64 tile.
// Output layout (b, n, s, k).
// ---------------------------------------------------------------------------
__global__ __launch_bounds__(256) void score_qk(
    const short* __restrict__ qbf, const short* __restrict__ kbf,
    const float* __restrict__ mask, float* __restrict__ scores)
{
    __shared__ short qa[64 * 72];
    __shared__ short kb[64 * 72];

    const int st = blockIdx.x, ktile = blockIdx.y, z = blockIdx.z;
    const int b = z / NH, n = z % NH;
    const int s0 = st * 64, k0 = ktile * 64;
    const int tid = threadIdx.x;
    const int w = tid >> 6, l = tid & 63;
    const int sr = tid >> 2, sc = (tid & 3) * 16;

    {
        const short8* sa = (const short8*)(qbf + (((size_t)(b * NH + n) * S_) + s0 + sr) * HD + sc);
        *(short8*)&qa[sr * 72 + sc]     = sa[0];
        *(short8*)&qa[sr * 72 + sc + 8] = sa[1];
        const short8* sb = (const short8*)(kbf + (((size_t)(b * NH + n) * S_) + k0 + sr) * HD + sc);
        *(short8*)&kb[sr * 72 + sc]     = sb[0];
        *(short8*)&kb[sr * 72 + sc + 8] = sb[1];
    }
    __syncthreads();

    f32x4 acc[4];
    #pragma unroll
    for (int i = 0; i < 4; ++i) acc[i] = (f32x4){0.f, 0.f, 0.f, 0.f};

    const int arow = (w * 16 + (l & 15)) * 72 + (l >> 4) * 8;
    short8 a0 = *(const short8*)&qa[arow];
    short8 a1 = *(const short8*)&qa[arow + 32];
    #pragma unroll
    for (int ct = 0; ct < 4; ++ct) {
        const int brow = (ct * 16 + (l & 15)) * 72 + (l >> 4) * 8;
        short8 b0 = *(const short8*)&kb[brow];
        short8 b1 = *(const short8*)&kb[brow + 32];
        acc[ct] = __builtin_amdgcn_mfma_f32_16x16x32_bf16(a0, b0, acc[ct], 0, 0, 0);
        acc[ct] = __builtin_amdgcn_mfma_f32_16x16x32_bf16(a1, b1, acc[ct], 0, 0, 0);
    }

    #pragma unroll
    for (int ct = 0; ct < 4; ++ct) {
        const float mv = mask[b * S_ + k0 + ct * 16 + (l & 15)];
        #pragma unroll
        for (int rr = 0; rr < 4; ++rr) {
            const int s_l = w * 16 + (l >> 4) * 4 + rr;
            scores[(((size_t)(b * NH + n) * S_) + s0 + s_l) * S_ + k0 + ct * 16 + (l & 15)]
                = acc[ct][rr] + mv;
        }
    }
}

// ---------------------------------------------------------------------------
// Kernel 3: rel contribution via async global_load_lds (zero-VGPR pipeline).
// Grid (kh=2, s=512, b=2) = 2048 blocks x 128 threads (2 waves).
// Wave w streams subtiles sk = kh*16 + t*2 + w, t=0..7. Per subtile:
// 12 async 1KB loads (3 tensors x 4) into a per-wave 12KB LDS slab,
// double-buffered; explicit vmcnt(0) one iteration after issue; XOR-swizzled
// source chunks + matching swizzled ds_read_b128 (bank-conflict-free, rule 21).
// rsum in fp32 regs -> bf16 B-fragment -> MFMA vs q A-fragment -> relsc.
// No __syncthreads anywhere (all dependencies wave-local).
// ---------------------------------------------------------------------------
__global__ __launch_bounds__(128) void score_rel(
    const short* __restrict__ qbf,
    const float* __restrict__ rel1, const float* __restrict__ rel2, const float* __restrict__ rel3,
    float* __restrict__ relsc)
{
    __shared__ float lds[2][2][3][1024];   // [wave][buf][tensor][4KB] = 48 KB

    const int kh = blockIdx.x;
    const int s  = blockIdx.y;
    const int b  = blockIdx.z;
    const int tid = threadIdx.x;
    const int w = tid >> 6, l = tid & 63;

    const int row = l & 15;          // A-row (head) / B-row (k) / D-col (k)
    const int g   = l >> 4;          // 0..3, h-chunk group
    const int sw  = row & 7;         // read-side XOR

    // q A-fragment (heads 12..15 zero), loaded once.
    short8 a0 = {0, 0, 0, 0, 0, 0, 0, 0};
    short8 a1 = {0, 0, 0, 0, 0, 0, 0, 0};
    if (row < NH) {
        const short* qp = qbf + (((size_t)(b * NH + row) * S_) + s) * HD;
        a0 = *(const short8*)(qp + g * 8);
        a1 = *(const short8*)(qp + g * 8 + 32);
    }

    const float* relp0 = rel1;
    const float* relp1 = rel2;
    const float* relp2 = rel3;
    const size_t bs = (size_t)(b * S_ + s) * S_;

    // Stage one 16-row subtile of all 3 tensors into buf. Source chunk is
    // XOR-swizzled by (row&7) so linear LDS + swizzled read = conflict-free.
    auto STAGE = [&](int buf, int sk) {
        const int lrow = (l >> 4);                 // 0..3 within 4-row group
        const int gch  = (l & 15);                 // chunk slot this lane fills
        #pragma unroll
        for (int j = 0; j < 4; ++j) {
            const int r  = j * 4 + lrow;           // local row 0..15
            const int ch = gch ^ (r & 7);          // swizzled source chunk
            const size_t go = (bs + (size_t)(sk * 16 + r)) * HD + ch * 4;
            gl16(relp0 + go, &lds[w][buf][0][j * 256]);
            gl16(relp1 + go, &lds[w][buf][1][j * 256]);
            gl16(relp2 + go, &lds[w][buf][2][j * 256]);
        }
    };

    STAGE(0, kh * 16 + w);           // prologue: subtile t=0

    for (int t = 0; t < 8; ++t) {
        const int buf = t & 1;
        const int sk  = kh * 16 + t * 2 + w;

        // Wait for this buffer's loads (issued one iteration ago, or in the
        // prologue). Next-tile loads are NOT yet issued, so this is cheap.
        asm volatile("s_waitcnt vmcnt(0)" ::: "memory");
        __builtin_amdgcn_sched_barrier(0);

        // Swizzled ds_read_b128: floats [row][g*8..+8) and [row][32+g*8..+8).
        float rs[16];
        #pragma unroll
        for (int T = 0; T < 3; ++T) {
            const float* bp = &lds[w][buf][T][row * 64];
            float4 v0 = *(const float4*)(bp + (((2 * g    ) ^ sw) << 2));
            float4 v1 = *(const float4*)(bp + (((2 * g + 1) ^ sw) << 2));
            float4 v2 = *(const float4*)(bp + (((2 * g + 8) ^ sw) << 2));
            float4 v3 = *(const float4*)(bp + (((2 * g + 9) ^ sw) << 2));
            if (T == 0) {
                rs[0] = v0.x;  rs[1] = v0.y;  rs[2]  = v0.z;  rs[3]  = v0.w;
                rs[4] = v1.x;  rs[5] = v1.y;  rs[6]  = v1.z;  rs[7]  = v1.w;
                rs[8] = v2.x;  rs[9] = v2.y;  rs[10] = v2.z;  rs[11] = v2.w;
                rs[12] = v3.x; rs[13] = v3.y; rs[14] = v3.z;  rs[15] = v3.w;
            } else {
                rs[0] += v0.x;  rs[1] += v0.y;  rs[2]  += v0.z;  rs[3]  += v0.w;
                rs[4] += v1.x;  rs[5] += v1.y;  rs[6]  += v1.z;  rs[7]  += v1.w;
                rs[8] += v2.x;  rs[9] += v2.y;  rs[10] += v2.z;  rs[11] += v2.w;
                rs[12] += v3.x; rs[13] += v3.y; rs[14] += v3.z;  rs[15] += v3.w;
            }
        }

        // Issue next subtile's async loads now (they fly during compute+store
        // and the next iteration's top).
        if (t < 7) STAGE(buf ^ 1, sk + 2);

        short8 b0 = {f2bf(rs[0]), f2bf(rs[1]), f2bf(rs[2]),  f2bf(rs[3]),
                     f2bf(rs[4]), f2bf(rs[5]), f2bf(rs[6]),  f2bf(rs[7])};
        short8 b1 = {f2bf(rs[8]), f2bf(rs[9]), f2bf(rs[10]), f2bf(rs[11]),
                     f2bf(rs[12]), f2bf(rs[13]), f2bf(rs[14]), f2bf(rs[15])};

        f32x4 acc = (f32x4){0.f, 0.f, 0.f, 0.f};
        acc = __builtin_amdgcn_mfma_f32_16x16x32_bf16(a0, b0, acc, 0, 0, 0);
        acc = __builtin_amdgcn_mfma_f32_16x16x32_bf16(a1, b1, acc, 0, 0, 0);

        const int kg = sk * 16 + row;    // D col = k
        #pragma unroll
        for (int rr = 0; rr < 4; ++rr) {
            const int n = g * 4 + rr;    // D row = head
            if (n < NH)
                relsc[(((size_t)(b * S_ + s)) * NH + n) * S_ + kg] = acc[rr];
        }
    }
}

// ---------------------------------------------------------------------------
// Kernel 4: fused softmax + PV (fp32). Grid (st=32, n=12, b=2).
// Reads qk-scores (b,n,s,k) + relsc (b,s,n,k), sums, softmaxes, PV.
// ---------------------------------------------------------------------------
__global__ __launch_bounds__(256) void smpv_kernel(
    const float* __restrict__ scores, const float* __restrict__ relsc,
    const float* __restrict__ vws, float* __restrict__ out)
{
    __shared__ float sc[16][512];

    const int st  = blockIdx.x;
    const int n   = blockIdx.y;
    const int b   = blockIdx.z;
    const int s0  = st * 16;
    const int tid = threadIdx.x;

    const size_t base = (((size_t)(b * NH + n) * S_) + s0) * S_;

    #pragma unroll
    for (int j = 0; j < 8; ++j) {
        const int fidx = j * 256 + tid;
        const int row  = fidx >> 7;
        const int c4   = fidx & 127;
        float4 v = *(const float4*)(scores + base + (size_t)row * S_ + c4 * 4);
        float4 r = *(const float4*)(relsc +
                    (((size_t)(b * S_ + s0 + row)) * NH + n) * S_ + c4 * 4);
        v.x += r.x; v.y += r.y; v.z += r.z; v.w += r.w;
        *(float4*)&sc[row][c4 * 4] = v;
    }
    __syncthreads();

    const int w = tid >> 6, lane = tid & 63;

    for (int r = 0; r < 4; ++r) {
        const int row = w * 4 + r;
        float vals[8];
        float m = -1e30f;
        #pragma unroll
        for (int i = 0; i < 8; ++i) { vals[i] = sc[row][lane + 64 * i]; m = fmaxf(m, vals[i]); }
        #pragma unroll
        for (int off = 32; off >= 1; off >>= 1) m = fmaxf(m, __shfl_xor(m, off));
        float sum = 0.f;
        #pragma unroll
        for (int i = 0; i < 8; ++i) { vals[i] = __expf(vals[i] - m); sum += vals[i]; }
        #pragma unroll
        for (int off = 32; off >= 1; off >>= 1) sum += __shfl_xor(sum, off);
        const float inv = 1.0f / sum;
        #pragma unroll
        for (int i = 0; i < 8; ++i) sc[row][lane + 64 * i] = vals[i] * inv;
    }
    __syncthreads();

    float acc[4] = {0.f, 0.f, 0.f, 0.f};
    const float* vb = vws + (((size_t)(b * NH + n) * S_)) * HD + lane;
    for (int k = 0; k < S_; k += 4) {
        const float v0 = vb[(size_t)(k + 0) * HD];
        const float v1 = vb[(size_t)(k + 1) * HD];
        const float v2 = vb[(size_t)(k + 2) * HD];
        const float v3 = vb[(size_t)(k + 3) * HD];
        #pragma unroll
        for (int r = 0; r < 4; ++r) {
            float4 p = *(const float4*)&sc[w * 4 + r][k];
            acc[r] += p.x * v0 + p.y * v1 + p.z * v2 + p.w * v3;
        }
    }
    #pragma unroll
    for (int r = 0; r < 4; ++r)
        out[((size_t)(b * S_ + s0 + w * 4 + r)) * D_ + n * HD + lane] = acc[r];
}

extern "C" void kernel_launch(void* const* d_in, const int* in_sizes, int n_in,
                              void* d_out, int out_size, void* d_ws, size_t ws_size,
                              hipStream_t stream) {
    const float* hidden = (const float*)d_in[0];
    const float* mask   = (const float*)d_in[1];
    const float* rel1   = (const float*)d_in[2];
    const float* rel2   = (const float*)d_in[3];
    const float* rel3   = (const float*)d_in[4];
    const float* Wq     = (const float*)d_in[5];
    const float* bq     = (const float*)d_in[6];
    const float* Wk     = (const float*)d_in[7];
    const float* bk     = (const float*)d_in[8];
    const float* Wv     = (const float*)d_in[9];
    const float* bv     = (const float*)d_in[10];
    float* out = (float*)d_out;

    const size_t per = (size_t)B_ * NH * S_ * HD;   // 786432
    short* qbf    = (short*)d_ws;                    // 1.5 MB
    short* kbf    = qbf + per;                       // 1.5 MB
    float* vws    = (float*)(kbf + per);             // 3 MB
    float* scores = vws + per;                       // 25 MB  (b,n,s,k)
    float* relsc  = scores + (size_t)B_ * NH * S_ * S_;  // 12.6 MB (b,s,n,k)

    qkv_gemm<<<dim3(16, 12, 3), 256, 0, stream>>>(hidden, Wq, Wk, Wv, bq, bk, bv, qbf, kbf, vws);
    score_qk<<<dim3(8, 8, 24), 256, 0, stream>>>(qbf, kbf, mask, scores);
    score_rel<<<dim3(2, S_, B_), 128, 0, stream>>>(qbf, rel1, rel2, rel3, relsc);
    smpv_kernel<<<dim3(S_ / 16, NH, B_), 256, 0, stream>>>(scores, relsc, vws, out);
}

// Round 8
// 147.458 us; speedup vs baseline: 1.1140x; 1.1140x over previous
//
#include <hip/hip_runtime.h>

typedef __attribute__((ext_vector_type(8))) short short8;
typedef __attribute__((ext_vector_type(4))) float f32x4;

#define B_ 2
#define S_ 512
#define D_ 768
#define NH 12
#define HD 64

__device__ inline short f2bf(float f) {
    union { float f; unsigned u; } v; v.f = f;
    unsigned r = v.u + 0x7fffu + ((v.u >> 16) & 1u);
    return (short)(r >> 16);
}

// ---------------------------------------------------------------------------
// Kernel 1: QKV projection, bf16 MFMA (16x16x32), fp32 accumulate.
// q -> qbf (bf16, pre-scaled 1/8), k -> kbf (bf16), v -> vws (fp32),
// all in (B, NH, S, HD) layout.
// ---------------------------------------------------------------------------
__global__ __launch_bounds__(256) void qkv_gemm(
    const float* __restrict__ hidden,
    const float* __restrict__ Wq, const float* __restrict__ Wk, const float* __restrict__ Wv,
    const float* __restrict__ bq, const float* __restrict__ bk, const float* __restrict__ bv,
    short* __restrict__ qbf, short* __restrict__ kbf, float* __restrict__ vws)
{
    __shared__ short hs[64 * 72];
    __shared__ short wt[64 * 72];

    const int mt = blockIdx.x, nt = blockIdx.y, mat = blockIdx.z;
    const int m0 = mt * 64, n0 = nt * 64;
    const float* W    = (mat == 0) ? Wq : ((mat == 1) ? Wk : Wv);
    const float* bias = (mat == 0) ? bq : ((mat == 1) ? bk : bv);

    const int tid = threadIdx.x;
    const int w = tid >> 6, l = tid & 63;
    const int sr = tid >> 2, sc = (tid & 3) * 16;

    f32x4 acc[4];
    #pragma unroll
    for (int i = 0; i < 4; ++i) acc[i] = (f32x4){0.f, 0.f, 0.f, 0.f};

    const int arow = (w * 16 + (l & 15)) * 72 + (l >> 4) * 8;

    for (int kt = 0; kt < 12; ++kt) {
        const int d0 = kt * 64;
        if (kt) __syncthreads();
        {
            const float4* sa = (const float4*)(hidden + (size_t)(m0 + sr) * D_ + d0 + sc);
            float4 x0 = sa[0], x1 = sa[1], x2 = sa[2], x3 = sa[3];
            short8 p0 = {f2bf(x0.x), f2bf(x0.y), f2bf(x0.z), f2bf(x0.w),
                         f2bf(x1.x), f2bf(x1.y), f2bf(x1.z), f2bf(x1.w)};
            short8 p1 = {f2bf(x2.x), f2bf(x2.y), f2bf(x2.z), f2bf(x2.w),
                         f2bf(x3.x), f2bf(x3.y), f2bf(x3.z), f2bf(x3.w)};
            *(short8*)&hs[sr * 72 + sc]     = p0;
            *(short8*)&hs[sr * 72 + sc + 8] = p1;
            const float4* sb = (const float4*)(W + (size_t)(n0 + sr) * D_ + d0 + sc);
            float4 y0 = sb[0], y1 = sb[1], y2 = sb[2], y3 = sb[3];
            short8 q0 = {f2bf(y0.x), f2bf(y0.y), f2bf(y0.z), f2bf(y0.w),
                         f2bf(y1.x), f2bf(y1.y), f2bf(y1.z), f2bf(y1.w)};
            short8 q1 = {f2bf(y2.x), f2bf(y2.y), f2bf(y2.z), f2bf(y2.w),
                         f2bf(y3.x), f2bf(y3.y), f2bf(y3.z), f2bf(y3.w)};
            *(short8*)&wt[sr * 72 + sc]     = q0;
            *(short8*)&wt[sr * 72 + sc + 8] = q1;
        }
        __syncthreads();
        short8 a0 = *(const short8*)&hs[arow];
        short8 a1 = *(const short8*)&hs[arow + 32];
        #pragma unroll
        for (int ct = 0; ct < 4; ++ct) {
            const int brow = (ct * 16 + (l & 15)) * 72 + (l >> 4) * 8;
            short8 b0 = *(const short8*)&wt[brow];
            short8 b1 = *(const short8*)&wt[brow + 32];
            acc[ct] = __builtin_amdgcn_mfma_f32_16x16x32_bf16(a0, b0, acc[ct], 0, 0, 0);
            acc[ct] = __builtin_amdgcn_mfma_f32_16x16x32_bf16(a1, b1, acc[ct], 0, 0, 0);
        }
    }

    #pragma unroll
    for (int ct = 0; ct < 4; ++ct) {
        #pragma unroll
        for (int rr = 0; rr < 4; ++rr) {
            const int m_l = w * 16 + (l >> 4) * 4 + rr;
            const int n_l = ct * 16 + (l & 15);
            const int m = m0 + m_l;
            const int b = m >> 9, s = m & 511;
            float v = acc[ct][rr] + bias[n0 + n_l];
            const size_t dst = (((size_t)(b * NH + nt) * S_) + s) * HD + n_l;
            if (mat == 0)      qbf[dst] = f2bf(v * 0.125f);
            else if (mat == 1) kbf[dst] = f2bf(v);
            else               vws[dst] = v;
        }
    }
}

// ---------------------------------------------------------------------------
// Kernel 2: rel contribution (R4 structure — proven fastest at the demand-read
// clamp). Grid (kt=8, s=512, b=2), 256 threads. One 16-k subtile per wave:
// 12 dwordx4 rel loads -> rsum -> bf16 B-fragment, MFMA vs q A-fragment,
// PURE STORE to relsc (b,s,n,k) fp32 — no RMW, no scores buffer.
// ---------------------------------------------------------------------------
__global__ __launch_bounds__(256) void score_rel(
    const short* __restrict__ qbf,
    const float* __restrict__ rel1, const float* __restrict__ rel2, const float* __restrict__ rel3,
    float* __restrict__ relsc)
{
    const int kt = blockIdx.x;       // 0..7
    const int s  = blockIdx.y;
    const int b  = blockIdx.z;
    const int tid = threadIdx.x;
    const int w = tid >> 6, l = tid & 63;

    const int rowsel = l & 15;       // A: n-row / B: k-row / D: k-col
    const int hc     = (l >> 4) * 8; // h-chunk base

    const int kc = kt * 4 + w;       // k-subtile 0..31
    const size_t rbase = ((size_t)(b * S_ + s)) * S_ * HD;
    const size_t ro = rbase + (size_t)(kc * 16 + rowsel) * HD + hc;

    float4 p0a = *(const float4*)(rel1 + ro);
    float4 p0b = *(const float4*)(rel1 + ro + 4);
    float4 q0a = *(const float4*)(rel1 + ro + 32);
    float4 q0b = *(const float4*)(rel1 + ro + 36);
    float4 p1a = *(const float4*)(rel2 + ro);
    float4 p1b = *(const float4*)(rel2 + ro + 4);
    float4 q1a = *(const float4*)(rel2 + ro + 32);
    float4 q1b = *(const float4*)(rel2 + ro + 36);
    float4 p2a = *(const float4*)(rel3 + ro);
    float4 p2b = *(const float4*)(rel3 + ro + 4);
    float4 q2a = *(const float4*)(rel3 + ro + 32);
    float4 q2b = *(const float4*)(rel3 + ro + 36);

    short8 a0 = {0, 0, 0, 0, 0, 0, 0, 0};
    short8 a1 = {0, 0, 0, 0, 0, 0, 0, 0};
    if (rowsel < NH) {
        const short* qp = qbf + (((size_t)(b * NH + rowsel) * S_) + s) * HD;
        a0 = *(const short8*)(qp + hc);
        a1 = *(const short8*)(qp + hc + 32);
    }

    short8 b0 = {
        f2bf(p0a.x + p1a.x + p2a.x), f2bf(p0a.y + p1a.y + p2a.y),
        f2bf(p0a.z + p1a.z + p2a.z), f2bf(p0a.w + p1a.w + p2a.w),
        f2bf(p0b.x + p1b.x + p2b.x), f2bf(p0b.y + p1b.y + p2b.y),
        f2bf(p0b.z + p1b.z + p2b.z), f2bf(p0b.w + p1b.w + p2b.w)};
    short8 b1 = {
        f2bf(q0a.x + q1a.x + q2a.x), f2bf(q0a.y + q1a.y + q2a.y),
        f2bf(q0a.z + q1a.z + q2a.z), f2bf(q0a.w + q1a.w + q2a.w),
        f2bf(q0b.x + q1b.x + q2b.x), f2bf(q0b.y + q1b.y + q2b.y),
        f2bf(q0b.z + q1b.z + q2b.z), f2bf(q0b.w + q1b.w + q2b.w)};

    f32x4 acc = (f32x4){0.f, 0.f, 0.f, 0.f};
    acc = __builtin_amdgcn_mfma_f32_16x16x32_bf16(a0, b0, acc, 0, 0, 0);
    acc = __builtin_amdgcn_mfma_f32_16x16x32_bf16(a1, b1, acc, 0, 0, 0);

    const int kg = kc * 16 + rowsel;
    #pragma unroll
    for (int rr = 0; rr < 4; ++rr) {
        const int n = (l >> 4) * 4 + rr;
        if (n < NH)
            relsc[(((size_t)(b * S_ + s)) * NH + n) * S_ + kg] = acc[rr];
    }
}

// ---------------------------------------------------------------------------
// Kernel 3: fused QK-MFMA + rel/mask add + softmax + PV.
// Grid (st=32, n=12, b=2) = 768 blocks, 256 threads, LDS 33.3 KB (4 blk/CU).
// QK: A = q[s0..s0+15][h] (one load), B = K straight from kbf (L2-resident,
// 3 MB total); each wave owns 8 k-tiles -> scores 16x512 in LDS.
// Then += relsc + mask, softmax per row, PV vs fp32 V.
// ---------------------------------------------------------------------------
__global__ __launch_bounds__(256) void smqkpv(
    const short* __restrict__ qbf, const short* __restrict__ kbf,
    const float* __restrict__ relsc, const float* __restrict__ mask,
    const float* __restrict__ vws, float* __restrict__ out)
{
    __shared__ float sc[16][520];    // pad 8: row stride 520 % 32 = 8

    const int st  = blockIdx.x;
    const int n   = blockIdx.y;
    const int b   = blockIdx.z;
    const int s0  = st * 16;
    const int tid = threadIdx.x;
    const int w = tid >> 6, l = tid & 63;

    // --- QK^T via MFMA ---
    const int arow = l & 15;         // A row (s_local) for loads / D col (k)
    const int g    = l >> 4;         // h-chunk / D row group

    const short* qp = qbf + (((size_t)(b * NH + n) * S_) + s0 + arow) * HD + g * 8;
    short8 a0 = *(const short8*)(qp);
    short8 a1 = *(const short8*)(qp + 32);

    f32x4 acc[8];
    #pragma unroll
    for (int t = 0; t < 8; ++t) acc[t] = (f32x4){0.f, 0.f, 0.f, 0.f};

    #pragma unroll
    for (int t = 0; t < 8; ++t) {
        const int k0 = (w * 8 + t) * 16;
        const short* kp = kbf + (((size_t)(b * NH + n) * S_) + k0 + arow) * HD + g * 8;
        short8 b0 = *(const short8*)(kp);
        short8 b1 = *(const short8*)(kp + 32);
        acc[t] = __builtin_amdgcn_mfma_f32_16x16x32_bf16(a0, b0, acc[t], 0, 0, 0);
        acc[t] = __builtin_amdgcn_mfma_f32_16x16x32_bf16(a1, b1, acc[t], 0, 0, 0);
    }

    #pragma unroll
    for (int t = 0; t < 8; ++t) {
        const int k0 = (w * 8 + t) * 16;
        #pragma unroll
        for (int rr = 0; rr < 4; ++rr)
            sc[g * 4 + rr][k0 + arow] = acc[t][rr];
    }
    __syncthreads();

    // --- += rel scores + mask ---
    #pragma unroll
    for (int j = 0; j < 8; ++j) {
        const int fidx = j * 256 + tid;
        const int row  = fidx >> 7;
        const int c4   = (fidx & 127) * 4;
        float4 r = *(const float4*)(relsc +
                    (((size_t)(b * S_ + s0 + row)) * NH + n) * S_ + c4);
        float4 mk = *(const float4*)(mask + b * S_ + c4);
        float4 cur = *(const float4*)&sc[row][c4];
        cur.x += r.x + mk.x; cur.y += r.y + mk.y;
        cur.z += r.z + mk.z; cur.w += r.w + mk.w;
        *(float4*)&sc[row][c4] = cur;
    }
    __syncthreads();

    // --- softmax per row (PB-Relax == plain softmax, shift-invariant) ---
    const int lane = l;
    for (int r = 0; r < 4; ++r) {
        const int row = w * 4 + r;
        float vals[8];
        float m = -1e30f;
        #pragma unroll
        for (int i = 0; i < 8; ++i) { vals[i] = sc[row][lane + 64 * i]; m = fmaxf(m, vals[i]); }
        #pragma unroll
        for (int off = 32; off >= 1; off >>= 1) m = fmaxf(m, __shfl_xor(m, off));
        float sum = 0.f;
        #pragma unroll
        for (int i = 0; i < 8; ++i) { vals[i] = __expf(vals[i] - m); sum += vals[i]; }
        #pragma unroll
        for (int off = 32; off >= 1; off >>= 1) sum += __shfl_xor(sum, off);
        const float inv = 1.0f / sum;
        #pragma unroll
        for (int i = 0; i < 8; ++i) sc[row][lane + 64 * i] = vals[i] * inv;
    }
    __syncthreads();

    // --- PV ---
    float pacc[4] = {0.f, 0.f, 0.f, 0.f};
    const float* vb = vws + (((size_t)(b * NH + n) * S_)) * HD + lane;
    for (int k = 0; k < S_; k += 4) {
        const float v0 = vb[(size_t)(k + 0) * HD];
        const float v1 = vb[(size_t)(k + 1) * HD];
        const float v2 = vb[(size_t)(k + 2) * HD];
        const float v3 = vb[(size_t)(k + 3) * HD];
        #pragma unroll
        for (int r = 0; r < 4; ++r) {
            float4 p = *(const float4*)&sc[w * 4 + r][k];
            pacc[r] += p.x * v0 + p.y * v1 + p.z * v2 + p.w * v3;
        }
    }
    #pragma unroll
    for (int r = 0; r < 4; ++r)
        out[((size_t)(b * S_ + s0 + w * 4 + r)) * D_ + n * HD + lane] = pacc[r];
}

extern "C" void kernel_launch(void* const* d_in, const int* in_sizes, int n_in,
                              void* d_out, int out_size, void* d_ws, size_t ws_size,
                              hipStream_t stream) {
    const float* hidden = (const float*)d_in[0];
    const float* mask   = (const float*)d_in[1];
    const float* rel1   = (const float*)d_in[2];
    const float* rel2   = (const float*)d_in[3];
    const float* rel3   = (const float*)d_in[4];
    const float* Wq     = (const float*)d_in[5];
    const float* bq     = (const float*)d_in[6];
    const float* Wk     = (const float*)d_in[7];
    const float* bk     = (const float*)d_in[8];
    const float* Wv     = (const float*)d_in[9];
    const float* bv     = (const float*)d_in[10];
    float* out = (float*)d_out;

    const size_t per = (size_t)B_ * NH * S_ * HD;   // 786432
    short* qbf   = (short*)d_ws;                     // 1.5 MB
    short* kbf   = qbf + per;                        // 1.5 MB
    float* vws   = (float*)(kbf + per);              // 3 MB
    float* relsc = vws + per;                        // 12.6 MB (b,s,n,k)

    qkv_gemm<<<dim3(16, 12, 3), 256, 0, stream>>>(hidden, Wq, Wk, Wv, bq, bk, bv, qbf, kbf, vws);
    score_rel<<<dim3(8, S_, B_), 256, 0, stream>>>(qbf, rel1, rel2, rel3, relsc);
    smqkpv<<<dim3(S_ / 16, NH, B_), 256, 0, stream>>>(qbf, kbf, relsc, mask, vws, out);
}

// Round 10
// 143.497 us; speedup vs baseline: 1.1447x; 1.0276x over previous
//
#include <hip/hip_runtime.h>

typedef __attribute__((ext_vector_type(8))) short short8;
typedef __attribute__((ext_vector_type(4))) float f32x4;

#define B_ 2
#define S_ 512
#define D_ 768
#define NH 12
#define HD 64

__device__ inline short f2bf(float f) {
    union { float f; unsigned u; } v; v.f = f;
    unsigned r = v.u + 0x7fffu + ((v.u >> 16) & 1u);
    return (short)(r >> 16);
}

__device__ __forceinline__ f32x4 ntload4(const float* p) {
    return __builtin_nontemporal_load((const f32x4*)p);
}

// ---------------------------------------------------------------------------
// Kernel 1: QKV projection, bf16 MFMA (16x16x32), fp32 accumulate.
// q -> qbf (bf16, pre-scaled 1/8), k -> kbf (bf16), v -> vws (fp32),
// all in (B, NH, S, HD) layout.
// ---------------------------------------------------------------------------
__global__ __launch_bounds__(256) void qkv_gemm(
    const float* __restrict__ hidden,
    const float* __restrict__ Wq, const float* __restrict__ Wk, const float* __restrict__ Wv,
    const float* __restrict__ bq, const float* __restrict__ bk, const float* __restrict__ bv,
    short* __restrict__ qbf, short* __restrict__ kbf, float* __restrict__ vws)
{
    __shared__ short hs[64 * 72];
    __shared__ short wt[64 * 72];

    const int mt = blockIdx.x, nt = blockIdx.y, mat = blockIdx.z;
    const int m0 = mt * 64, n0 = nt * 64;
    const float* W    = (mat == 0) ? Wq : ((mat == 1) ? Wk : Wv);
    const float* bias = (mat == 0) ? bq : ((mat == 1) ? bk : bv);

    const int tid = threadIdx.x;
    const int w = tid >> 6, l = tid & 63;
    const int sr = tid >> 2, sc = (tid & 3) * 16;

    f32x4 acc[4];
    #pragma unroll
    for (int i = 0; i < 4; ++i) acc[i] = (f32x4){0.f, 0.f, 0.f, 0.f};

    const int arow = (w * 16 + (l & 15)) * 72 + (l >> 4) * 8;

    for (int kt = 0; kt < 12; ++kt) {
        const int d0 = kt * 64;
        if (kt) __syncthreads();
        {
            const float4* sa = (const float4*)(hidden + (size_t)(m0 + sr) * D_ + d0 + sc);
            float4 x0 = sa[0], x1 = sa[1], x2 = sa[2], x3 = sa[3];
            short8 p0 = {f2bf(x0.x), f2bf(x0.y), f2bf(x0.z), f2bf(x0.w),
                         f2bf(x1.x), f2bf(x1.y), f2bf(x1.z), f2bf(x1.w)};
            short8 p1 = {f2bf(x2.x), f2bf(x2.y), f2bf(x2.z), f2bf(x2.w),
                         f2bf(x3.x), f2bf(x3.y), f2bf(x3.z), f2bf(x3.w)};
            *(short8*)&hs[sr * 72 + sc]     = p0;
            *(short8*)&hs[sr * 72 + sc + 8] = p1;
            const float4* sb = (const float4*)(W + (size_t)(n0 + sr) * D_ + d0 + sc);
            float4 y0 = sb[0], y1 = sb[1], y2 = sb[2], y3 = sb[3];
            short8 q0 = {f2bf(y0.x), f2bf(y0.y), f2bf(y0.z), f2bf(y0.w),
                         f2bf(y1.x), f2bf(y1.y), f2bf(y1.z), f2bf(y1.w)};
            short8 q1 = {f2bf(y2.x), f2bf(y2.y), f2bf(y2.z), f2bf(y2.w),
                         f2bf(y3.x), f2bf(y3.y), f2bf(y3.z), f2bf(y3.w)};
            *(short8*)&wt[sr * 72 + sc]     = q0;
            *(short8*)&wt[sr * 72 + sc + 8] = q1;
        }
        __syncthreads();
        short8 a0 = *(const short8*)&hs[arow];
        short8 a1 = *(const short8*)&hs[arow + 32];
        #pragma unroll
        for (int ct = 0; ct < 4; ++ct) {
            const int brow = (ct * 16 + (l & 15)) * 72 + (l >> 4) * 8;
            short8 b0 = *(const short8*)&wt[brow];
            short8 b1 = *(const short8*)&wt[brow + 32];
            acc[ct] = __builtin_amdgcn_mfma_f32_16x16x32_bf16(a0, b0, acc[ct], 0, 0, 0);
            acc[ct] = __builtin_amdgcn_mfma_f32_16x16x32_bf16(a1, b1, acc[ct], 0, 0, 0);
        }
    }

    #pragma unroll
    for (int ct = 0; ct < 4; ++ct) {
        #pragma unroll
        for (int rr = 0; rr < 4; ++rr) {
            const int m_l = w * 16 + (l >> 4) * 4 + rr;
            const int n_l = ct * 16 + (l & 15);
            const int m = m0 + m_l;
            const int b = m >> 9, s = m & 511;
            float v = acc[ct][rr] + bias[n0 + n_l];
            const size_t dst = (((size_t)(b * NH + nt) * S_) + s) * HD + n_l;
            if (mat == 0)      qbf[dst] = f2bf(v * 0.125f);
            else if (mat == 1) kbf[dst] = f2bf(v);
            else               vws[dst] = v;
        }
    }
}

// ---------------------------------------------------------------------------
// Kernel 2: rel contribution (R4 structure) with NON-TEMPORAL rel loads:
// bypass L2/L3 allocation so the 402 MB stream comes straight from HBM at
// pure-read rate instead of grinding through the L3-hit path.
// Grid (kt=8, s=512, b=2), 256 threads. One 16-k subtile per wave.
// ---------------------------------------------------------------------------
__global__ __launch_bounds__(256) void score_rel(
    const short* __restrict__ qbf,
    const float* __restrict__ rel1, const float* __restrict__ rel2, const float* __restrict__ rel3,
    float* __restrict__ relsc)
{
    const int kt = blockIdx.x;       // 0..7
    const int s  = blockIdx.y;
    const int b  = blockIdx.z;
    const int tid = threadIdx.x;
    const int w = tid >> 6, l = tid & 63;

    const int rowsel = l & 15;       // A: n-row / B: k-row / D: k-col
    const int hc     = (l >> 4) * 8; // h-chunk base

    const int kc = kt * 4 + w;       // k-subtile 0..31
    const size_t rbase = ((size_t)(b * S_ + s)) * S_ * HD;
    const size_t ro = rbase + (size_t)(kc * 16 + rowsel) * HD + hc;

    f32x4 p0a = ntload4(rel1 + ro);
    f32x4 p0b = ntload4(rel1 + ro + 4);
    f32x4 q0a = ntload4(rel1 + ro + 32);
    f32x4 q0b = ntload4(rel1 + ro + 36);
    f32x4 p1a = ntload4(rel2 + ro);
    f32x4 p1b = ntload4(rel2 + ro + 4);
    f32x4 q1a = ntload4(rel2 + ro + 32);
    f32x4 q1b = ntload4(rel2 + ro + 36);
    f32x4 p2a = ntload4(rel3 + ro);
    f32x4 p2b = ntload4(rel3 + ro + 4);
    f32x4 q2a = ntload4(rel3 + ro + 32);
    f32x4 q2b = ntload4(rel3 + ro + 36);

    short8 a0 = {0, 0, 0, 0, 0, 0, 0, 0};
    short8 a1 = {0, 0, 0, 0, 0, 0, 0, 0};
    if (rowsel < NH) {
        const short* qp = qbf + (((size_t)(b * NH + rowsel) * S_) + s) * HD;
        a0 = *(const short8*)(qp + hc);
        a1 = *(const short8*)(qp + hc + 32);
    }

    short8 b0 = {
        f2bf(p0a.x + p1a.x + p2a.x), f2bf(p0a.y + p1a.y + p2a.y),
        f2bf(p0a.z + p1a.z + p2a.z), f2bf(p0a.w + p1a.w + p2a.w),
        f2bf(p0b.x + p1b.x + p2b.x), f2bf(p0b.y + p1b.y + p2b.y),
        f2bf(p0b.z + p1b.z + p2b.z), f2bf(p0b.w + p1b.w + p2b.w)};
    short8 b1 = {
        f2bf(q0a.x + q1a.x + q2a.x), f2bf(q0a.y + q1a.y + q2a.y),
        f2bf(q0a.z + q1a.z + q2a.z), f2bf(q0a.w + q1a.w + q2a.w),
        f2bf(q0b.x + q1b.x + q2b.x), f2bf(q0b.y + q1b.y + q2b.y),
        f2bf(q0b.z + q1b.z + q2b.z), f2bf(q0b.w + q1b.w + q2b.w)};

    f32x4 acc = (f32x4){0.f, 0.f, 0.f, 0.f};
    acc = __builtin_amdgcn_mfma_f32_16x16x32_bf16(a0, b0, acc, 0, 0, 0);
    acc = __builtin_amdgcn_mfma_f32_16x16x32_bf16(a1, b1, acc, 0, 0, 0);

    const int kg = kc * 16 + rowsel;
    #pragma unroll
    for (int rr = 0; rr < 4; ++rr) {
        const int n = (l >> 4) * 4 + rr;
        if (n < NH) {
            float* p = relsc + (((size_t)(b * S_ + s)) * NH + n) * S_ + kg;
            __builtin_nontemporal_store(acc[rr], p);
        }
    }
}

// ---------------------------------------------------------------------------
// Kernel 3: fused QK-MFMA + rel/mask add + softmax + PV.
// Grid (st=32, n=12, b=2) = 768 blocks, 256 threads, LDS 33.3 KB.
// ---------------------------------------------------------------------------
__global__ __launch_bounds__(256) void smqkpv(
    const short* __restrict__ qbf, const short* __restrict__ kbf,
    const float* __restrict__ relsc, const float* __restrict__ mask,
    const float* __restrict__ vws, float* __restrict__ out)
{
    __shared__ float sc[16][520];    // pad 8: row stride 520 % 32 = 8

    const int st  = blockIdx.x;
    const int n   = blockIdx.y;
    const int b   = blockIdx.z;
    const int s0  = st * 16;
    const int tid = threadIdx.x;
    const int w = tid >> 6, l = tid & 63;

    // --- QK^T via MFMA ---
    const int arow = l & 15;         // A row (s_local) for loads / D col (k)
    const int g    = l >> 4;         // h-chunk / D row group

    const short* qp = qbf + (((size_t)(b * NH + n) * S_) + s0 + arow) * HD + g * 8;
    short8 a0 = *(const short8*)(qp);
    short8 a1 = *(const short8*)(qp + 32);

    f32x4 acc[8];
    #pragma unroll
    for (int t = 0; t < 8; ++t) acc[t] = (f32x4){0.f, 0.f, 0.f, 0.f};

    #pragma unroll
    for (int t = 0; t < 8; ++t) {
        const int k0 = (w * 8 + t) * 16;
        const short* kp = kbf + (((size_t)(b * NH + n) * S_) + k0 + arow) * HD + g * 8;
        short8 b0 = *(const short8*)(kp);
        short8 b1 = *(const short8*)(kp + 32);
        acc[t] = __builtin_amdgcn_mfma_f32_16x16x32_bf16(a0, b0, acc[t], 0, 0, 0);
        acc[t] = __builtin_amdgcn_mfma_f32_16x16x32_bf16(a1, b1, acc[t], 0, 0, 0);
    }

    #pragma unroll
    for (int t = 0; t < 8; ++t) {
        const int k0 = (w * 8 + t) * 16;
        #pragma unroll
        for (int rr = 0; rr < 4; ++rr)
            sc[g * 4 + rr][k0 + arow] = acc[t][rr];
    }
    __syncthreads();

    // --- += rel scores + mask ---
    #pragma unroll
    for (int j = 0; j < 8; ++j) {
        const int fidx = j * 256 + tid;
        const int row  = fidx >> 7;
        const int c4   = (fidx & 127) * 4;
        float4 r = *(const float4*)(relsc +
                    (((size_t)(b * S_ + s0 + row)) * NH + n) * S_ + c4);
        float4 mk = *(const float4*)(mask + b * S_ + c4);
        float4 cur = *(const float4*)&sc[row][c4];
        cur.x += r.x + mk.x; cur.y += r.y + mk.y;
        cur.z += r.z + mk.z; cur.w += r.w + mk.w;
        *(float4*)&sc[row][c4] = cur;
    }
    __syncthreads();

    // --- softmax per row (PB-Relax == plain softmax, shift-invariant) ---
    const int lane = l;
    for (int r = 0; r < 4; ++r) {
        const int row = w * 4 + r;
        float vals[8];
        float m = -1e30f;
        #pragma unroll
        for (int i = 0; i < 8; ++i) { vals[i] = sc[row][lane + 64 * i]; m = fmaxf(m, vals[i]); }
        #pragma unroll
        for (int off = 32; off >= 1; off >>= 1) m = fmaxf(m, __shfl_xor(m, off));
        float sum = 0.f;
        #pragma unroll
        for (int i = 0; i < 8; ++i) { vals[i] = __expf(vals[i] - m); sum += vals[i]; }
        #pragma unroll
        for (int off = 32; off >= 1; off >>= 1) sum += __shfl_xor(sum, off);
        const float inv = 1.0f / sum;
        #pragma unroll
        for (int i = 0; i < 8; ++i) sc[row][lane + 64 * i] = vals[i] * inv;
    }
    __syncthreads();

    // --- PV ---
    float pacc[4] = {0.f, 0.f, 0.f, 0.f};
    const float* vb = vws + (((size_t)(b * NH + n) * S_)) * HD + lane;
    for (int k = 0; k < S_; k += 4) {
        const float v0 = vb[(size_t)(k + 0) * HD];
        const float v1 = vb[(size_t)(k + 1) * HD];
        const float v2 = vb[(size_t)(k + 2) * HD];
        const float v3 = vb[(size_t)(k + 3) * HD];
        #pragma unroll
        for (int r = 0; r < 4; ++r) {
            float4 p = *(const float4*)&sc[w * 4 + r][k];
            pacc[r] += p.x * v0 + p.y * v1 + p.z * v2 + p.w * v3;
        }
    }
    #pragma unroll
    for (int r = 0; r < 4; ++r)
        out[((size_t)(b * S_ + s0 + w * 4 + r)) * D_ + n * HD + lane] = pacc[r];
}

extern "C" void kernel_launch(void* const* d_in, const int* in_sizes, int n_in,
                              void* d_out, int out_size, void* d_ws, size_t ws_size,
                              hipStream_t stream) {
    const float* hidden = (const float*)d_in[0];
    const float* mask   = (const float*)d_in[1];
    const float* rel1   = (const float*)d_in[2];
    const float* rel2   = (const float*)d_in[3];
    const float* rel3   = (const float*)d_in[4];
    const float* Wq     = (const float*)d_in[5];
    const float* bq     = (const float*)d_in[6];
    const float* Wk     = (const float*)d_in[7];
    const float* bk     = (const float*)d_in[8];
    const float* Wv     = (const float*)d_in[9];
    const float* bv     = (const float*)d_in[10];
    float* out = (float*)d_out;

    const size_t per = (size_t)B_ * NH * S_ * HD;   // 786432
    short* qbf   = (short*)d_ws;                     // 1.5 MB
    short* kbf   = qbf + per;                        // 1.5 MB
    float* vws   = (float*)(kbf + per);              // 3 MB
    float* relsc = vws + per;                        // 12.6 MB (b,s,n,k)

    qkv_gemm<<<dim3(16, 12, 3), 256, 0, stream>>>(hidden, Wq, Wk, Wv, bq, bk, bv, qbf, kbf, vws);
    score_rel<<<dim3(8, S_, B_), 256, 0, stream>>>(qbf, rel1, rel2, rel3, relsc);
    smqkpv<<<dim3(S_ / 16, NH, B_), 256, 0, stream>>>(qbf, kbf, relsc, mask, vws, out);
}

// Round 11
// 128.876 us; speedup vs baseline: 1.2746x; 1.1134x over previous
//
#include <hip/hip_runtime.h>

typedef __attribute__((ext_vector_type(8))) short short8;
typedef __attribute__((ext_vector_type(4))) float f32x4;

#define B_ 2
#define S_ 512
#define D_ 768
#define NH 12
#define HD 64

__device__ inline short f2bf(float f) {
    union { float f; unsigned u; } v; v.f = f;
    unsigned r = v.u + 0x7fffu + ((v.u >> 16) & 1u);
    return (short)(r >> 16);
}

__device__ __forceinline__ f32x4 ntload4(const float* p) {
    return __builtin_nontemporal_load((const f32x4*)p);
}

// ---------------------------------------------------------------------------
// Kernel 1: QKV projection, bf16 MFMA, fp32 accumulate.
// q -> qbf (bf16, scaled 1/8) (b,n,s,h); k -> kbf (bf16) (b,n,s,h);
// v -> vbf (bf16, TRANSPOSED) (b,n,h,s) via LDS transpose.
// ---------------------------------------------------------------------------
__global__ __launch_bounds__(256) void qkv_gemm(
    const float* __restrict__ hidden,
    const float* __restrict__ Wq, const float* __restrict__ Wk, const float* __restrict__ Wv,
    const float* __restrict__ bq, const float* __restrict__ bk, const float* __restrict__ bv,
    short* __restrict__ qbf, short* __restrict__ kbf, short* __restrict__ vbf)
{
    __shared__ short hs[64 * 72];
    __shared__ short wt[64 * 72];

    const int mt = blockIdx.x, nt = blockIdx.y, mat = blockIdx.z;
    const int m0 = mt * 64, n0 = nt * 64;
    const float* W    = (mat == 0) ? Wq : ((mat == 1) ? Wk : Wv);
    const float* bias = (mat == 0) ? bq : ((mat == 1) ? bk : bv);

    const int tid = threadIdx.x;
    const int w = tid >> 6, l = tid & 63;
    const int sr = tid >> 2, sc = (tid & 3) * 16;

    f32x4 acc[4];
    #pragma unroll
    for (int i = 0; i < 4; ++i) acc[i] = (f32x4){0.f, 0.f, 0.f, 0.f};

    const int arow = (w * 16 + (l & 15)) * 72 + (l >> 4) * 8;

    for (int kt = 0; kt < 12; ++kt) {
        const int d0 = kt * 64;
        if (kt) __syncthreads();
        {
            const float4* sa = (const float4*)(hidden + (size_t)(m0 + sr) * D_ + d0 + sc);
            float4 x0 = sa[0], x1 = sa[1], x2 = sa[2], x3 = sa[3];
            short8 p0 = {f2bf(x0.x), f2bf(x0.y), f2bf(x0.z), f2bf(x0.w),
                         f2bf(x1.x), f2bf(x1.y), f2bf(x1.z), f2bf(x1.w)};
            short8 p1 = {f2bf(x2.x), f2bf(x2.y), f2bf(x2.z), f2bf(x2.w),
                         f2bf(x3.x), f2bf(x3.y), f2bf(x3.z), f2bf(x3.w)};
            *(short8*)&hs[sr * 72 + sc]     = p0;
            *(short8*)&hs[sr * 72 + sc + 8] = p1;
            const float4* sb = (const float4*)(W + (size_t)(n0 + sr) * D_ + d0 + sc);
            float4 y0 = sb[0], y1 = sb[1], y2 = sb[2], y3 = sb[3];
            short8 q0 = {f2bf(y0.x), f2bf(y0.y), f2bf(y0.z), f2bf(y0.w),
                         f2bf(y1.x), f2bf(y1.y), f2bf(y1.z), f2bf(y1.w)};
            short8 q1 = {f2bf(y2.x), f2bf(y2.y), f2bf(y2.z), f2bf(y2.w),
                         f2bf(y3.x), f2bf(y3.y), f2bf(y3.z), f2bf(y3.w)};
            *(short8*)&wt[sr * 72 + sc]     = q0;
            *(short8*)&wt[sr * 72 + sc + 8] = q1;
        }
        __syncthreads();
        short8 a0 = *(const short8*)&hs[arow];
        short8 a1 = *(const short8*)&hs[arow + 32];
        #pragma unroll
        for (int ct = 0; ct < 4; ++ct) {
            const int brow = (ct * 16 + (l & 15)) * 72 + (l >> 4) * 8;
            short8 b0 = *(const short8*)&wt[brow];
            short8 b1 = *(const short8*)&wt[brow + 32];
            acc[ct] = __builtin_amdgcn_mfma_f32_16x16x32_bf16(a0, b0, acc[ct], 0, 0, 0);
            acc[ct] = __builtin_amdgcn_mfma_f32_16x16x32_bf16(a1, b1, acc[ct], 0, 0, 0);
        }
    }

    if (mat == 2) {
        // V: stage bf16 into LDS transposed [h][s_local], then coalesced store
        // to vbf (b, n, h, s).
        __syncthreads();
        #pragma unroll
        for (int ct = 0; ct < 4; ++ct) {
            #pragma unroll
            for (int rr = 0; rr < 4; ++rr) {
                const int m_l = w * 16 + (l >> 4) * 4 + rr;
                const int n_l = ct * 16 + (l & 15);
                hs[n_l * 68 + m_l] = f2bf(acc[ct][rr] + bias[n0 + n_l]);
            }
        }
        __syncthreads();
        const int b   = m0 >> 9;
        const int s0b = m0 & 511;
        #pragma unroll
        for (int j = 0; j < 2; ++j) {
            const int idx  = j * 256 + tid;      // 0..511
            const int h    = idx >> 3;           // 0..63
            const int sseg = (idx & 7) * 8;
            short8 vv = *(const short8*)&hs[h * 68 + sseg];
            *(short8*)(vbf + ((size_t)(b * NH + nt) * HD + h) * S_ + s0b + sseg) = vv;
        }
    } else {
        #pragma unroll
        for (int ct = 0; ct < 4; ++ct) {
            #pragma unroll
            for (int rr = 0; rr < 4; ++rr) {
                const int m_l = w * 16 + (l >> 4) * 4 + rr;
                const int n_l = ct * 16 + (l & 15);
                const int m = m0 + m_l;
                const int b = m >> 9, s = m & 511;
                float v = acc[ct][rr] + bias[n0 + n_l];
                const size_t dst = (((size_t)(b * NH + nt) * S_) + s) * HD + n_l;
                if (mat == 0) qbf[dst] = f2bf(v * 0.125f);
                else          kbf[dst] = f2bf(v);
            }
        }
    }
}

// ---------------------------------------------------------------------------
// Kernel 2: rel contribution, NT rel loads (proven +50% at the demand clamp).
// Grid (kt=8, s=512, b=2), 256 threads. One 16-k subtile per wave.
// Normal store to relsc (L2/L3-resident for the consumer).
// ---------------------------------------------------------------------------
__global__ __launch_bounds__(256) void score_rel(
    const short* __restrict__ qbf,
    const float* __restrict__ rel1, const float* __restrict__ rel2, const float* __restrict__ rel3,
    float* __restrict__ relsc)
{
    const int kt = blockIdx.x;       // 0..7
    const int s  = blockIdx.y;
    const int b  = blockIdx.z;
    const int tid = threadIdx.x;
    const int w = tid >> 6, l = tid & 63;

    const int rowsel = l & 15;       // A: n-row / B: k-row / D: k-col
    const int hc     = (l >> 4) * 8; // h-chunk base

    const int kc = kt * 4 + w;       // k-subtile 0..31
    const size_t rbase = ((size_t)(b * S_ + s)) * S_ * HD;
    const size_t ro = rbase + (size_t)(kc * 16 + rowsel) * HD + hc;

    f32x4 p0a = ntload4(rel1 + ro);
    f32x4 p0b = ntload4(rel1 + ro + 4);
    f32x4 q0a = ntload4(rel1 + ro + 32);
    f32x4 q0b = ntload4(rel1 + ro + 36);
    f32x4 p1a = ntload4(rel2 + ro);
    f32x4 p1b = ntload4(rel2 + ro + 4);
    f32x4 q1a = ntload4(rel2 + ro + 32);
    f32x4 q1b = ntload4(rel2 + ro + 36);
    f32x4 p2a = ntload4(rel3 + ro);
    f32x4 p2b = ntload4(rel3 + ro + 4);
    f32x4 q2a = ntload4(rel3 + ro + 32);
    f32x4 q2b = ntload4(rel3 + ro + 36);

    short8 a0 = {0, 0, 0, 0, 0, 0, 0, 0};
    short8 a1 = {0, 0, 0, 0, 0, 0, 0, 0};
    if (rowsel < NH) {
        const short* qp = qbf + (((size_t)(b * NH + rowsel) * S_) + s) * HD;
        a0 = *(const short8*)(qp + hc);
        a1 = *(const short8*)(qp + hc + 32);
    }

    short8 b0 = {
        f2bf(p0a.x + p1a.x + p2a.x), f2bf(p0a.y + p1a.y + p2a.y),
        f2bf(p0a.z + p1a.z + p2a.z), f2bf(p0a.w + p1a.w + p2a.w),
        f2bf(p0b.x + p1b.x + p2b.x), f2bf(p0b.y + p1b.y + p2b.y),
        f2bf(p0b.z + p1b.z + p2b.z), f2bf(p0b.w + p1b.w + p2b.w)};
    short8 b1 = {
        f2bf(q0a.x + q1a.x + q2a.x), f2bf(q0a.y + q1a.y + q2a.y),
        f2bf(q0a.z + q1a.z + q2a.z), f2bf(q0a.w + q1a.w + q2a.w),
        f2bf(q0b.x + q1b.x + q2b.x), f2bf(q0b.y + q1b.y + q2b.y),
        f2bf(q0b.z + q1b.z + q2b.z), f2bf(q0b.w + q1b.w + q2b.w)};

    f32x4 acc = (f32x4){0.f, 0.f, 0.f, 0.f};
    acc = __builtin_amdgcn_mfma_f32_16x16x32_bf16(a0, b0, acc, 0, 0, 0);
    acc = __builtin_amdgcn_mfma_f32_16x16x32_bf16(a1, b1, acc, 0, 0, 0);

    const int kg = kc * 16 + rowsel;
    #pragma unroll
    for (int rr = 0; rr < 4; ++rr) {
        const int n = (l >> 4) * 4 + rr;
        if (n < NH)
            relsc[(((size_t)(b * S_ + s)) * NH + n) * S_ + kg] = acc[rr];
    }
}

// ---------------------------------------------------------------------------
// Kernel 3: fused QK-MFMA + rel/mask add + softmax + MFMA-PV (bf16 P, V^T).
// Grid (st=32, n=12, b=2) = 768 blocks, 256 threads, LDS ~50 KB (3 blk/CU).
// ---------------------------------------------------------------------------
__global__ __launch_bounds__(256) void smqkpv(
    const short* __restrict__ qbf, const short* __restrict__ kbf,
    const float* __restrict__ relsc, const float* __restrict__ mask,
    const short* __restrict__ vbf, float* __restrict__ out)
{
    __shared__ float sc[16][520];    // fp32 scores, pad 8
    __shared__ short pbf[16][520];   // bf16 probs,  pad 8

    const int st  = blockIdx.x;
    const int n   = blockIdx.y;
    const int b   = blockIdx.z;
    const int s0  = st * 16;
    const int tid = threadIdx.x;
    const int w = tid >> 6, l = tid & 63;

    // --- QK^T via MFMA ---
    const int arow = l & 15;         // A row (s_local) / B col (k) / D col
    const int g    = l >> 4;         // h-chunk group / D row group

    const short* qp = qbf + (((size_t)(b * NH + n) * S_) + s0 + arow) * HD + g * 8;
    short8 a0 = *(const short8*)(qp);
    short8 a1 = *(const short8*)(qp + 32);

    f32x4 acc[8];
    #pragma unroll
    for (int t = 0; t < 8; ++t) acc[t] = (f32x4){0.f, 0.f, 0.f, 0.f};

    #pragma unroll
    for (int t = 0; t < 8; ++t) {
        const int k0 = (w * 8 + t) * 16;
        const short* kp = kbf + (((size_t)(b * NH + n) * S_) + k0 + arow) * HD + g * 8;
        short8 b0 = *(const short8*)(kp);
        short8 b1 = *(const short8*)(kp + 32);
        acc[t] = __builtin_amdgcn_mfma_f32_16x16x32_bf16(a0, b0, acc[t], 0, 0, 0);
        acc[t] = __builtin_amdgcn_mfma_f32_16x16x32_bf16(a1, b1, acc[t], 0, 0, 0);
    }

    #pragma unroll
    for (int t = 0; t < 8; ++t) {
        const int k0 = (w * 8 + t) * 16;
        #pragma unroll
        for (int rr = 0; rr < 4; ++rr)
            sc[g * 4 + rr][k0 + arow] = acc[t][rr];
    }
    __syncthreads();

    // --- += rel scores + mask ---
    #pragma unroll
    for (int j = 0; j < 8; ++j) {
        const int fidx = j * 256 + tid;
        const int row  = fidx >> 7;
        const int c4   = (fidx & 127) * 4;
        float4 r = *(const float4*)(relsc +
                    (((size_t)(b * S_ + s0 + row)) * NH + n) * S_ + c4);
        float4 mk = *(const float4*)(mask + b * S_ + c4);
        float4 cur = *(const float4*)&sc[row][c4];
        cur.x += r.x + mk.x; cur.y += r.y + mk.y;
        cur.z += r.z + mk.z; cur.w += r.w + mk.w;
        *(float4*)&sc[row][c4] = cur;
    }
    __syncthreads();

    // --- softmax per row; write normalized probs as bf16 into pbf ---
    const int lane = l;
    for (int r = 0; r < 4; ++r) {
        const int row = w * 4 + r;
        float vals[8];
        float m = -1e30f;
        #pragma unroll
        for (int i = 0; i < 8; ++i) { vals[i] = sc[row][lane + 64 * i]; m = fmaxf(m, vals[i]); }
        #pragma unroll
        for (int off = 32; off >= 1; off >>= 1) m = fmaxf(m, __shfl_xor(m, off));
        float sum = 0.f;
        #pragma unroll
        for (int i = 0; i < 8; ++i) { vals[i] = __expf(vals[i] - m); sum += vals[i]; }
        #pragma unroll
        for (int off = 32; off >= 1; off >>= 1) sum += __shfl_xor(sum, off);
        const float inv = 1.0f / sum;
        #pragma unroll
        for (int i = 0; i < 8; ++i) pbf[row][lane + 64 * i] = f2bf(vals[i] * inv);
    }
    __syncthreads();

    // --- PV via MFMA: out[s][h] = sum_k P[s][k] V^T[h][k]. Wave w owns
    // h-tile w (16 h). 16 K-steps of 32. ---
    f32x4 pacc = (f32x4){0.f, 0.f, 0.f, 0.f};
    const short* vrow = vbf + ((size_t)(b * NH + n) * HD + w * 16 + arow) * S_ + g * 8;
    #pragma unroll
    for (int kk = 0; kk < 16; ++kk) {
        short8 aP = *(const short8*)&pbf[arow][kk * 32 + g * 8];
        short8 bV = *(const short8*)(vrow + kk * 32);
        pacc = __builtin_amdgcn_mfma_f32_16x16x32_bf16(aP, bV, pacc, 0, 0, 0);
    }
    #pragma unroll
    for (int rr = 0; rr < 4; ++rr) {
        const int srow = g * 4 + rr;
        out[((size_t)(b * S_ + s0 + srow)) * D_ + n * HD + w * 16 + arow] = pacc[rr];
    }
}

extern "C" void kernel_launch(void* const* d_in, const int* in_sizes, int n_in,
                              void* d_out, int out_size, void* d_ws, size_t ws_size,
                              hipStream_t stream) {
    const float* hidden = (const float*)d_in[0];
    const float* mask   = (const float*)d_in[1];
    const float* rel1   = (const float*)d_in[2];
    const float* rel2   = (const float*)d_in[3];
    const float* rel3   = (const float*)d_in[4];
    const float* Wq     = (const float*)d_in[5];
    const float* bq     = (const float*)d_in[6];
    const float* Wk     = (const float*)d_in[7];
    const float* bk     = (const float*)d_in[8];
    const float* Wv     = (const float*)d_in[9];
    const float* bv     = (const float*)d_in[10];
    float* out = (float*)d_out;

    const size_t per = (size_t)B_ * NH * S_ * HD;   // 786432
    short* qbf   = (short*)d_ws;                     // 1.5 MB
    short* kbf   = qbf + per;                        // 1.5 MB
    short* vbf   = kbf + per;                        // 1.5 MB (b,n,h,s)
    float* relsc = (float*)(vbf + per);              // 12.6 MB (b,s,n,k)

    qkv_gemm<<<dim3(16, 12, 3), 256, 0, stream>>>(hidden, Wq, Wk, Wv, bq, bk, bv, qbf, kbf, vbf);
    score_rel<<<dim3(8, S_, B_), 256, 0, stream>>>(qbf, rel1, rel2, rel3, relsc);
    smqkpv<<<dim3(S_ / 16, NH, B_), 256, 0, stream>>>(qbf, kbf, relsc, mask, vbf, out);
}